// Round 8
// baseline (330.439 us; speedup 1.0000x reference)
//
#include <hip/hip_runtime.h>
#include <hip/hip_bf16.h>

#define NUM_NODES 100000
#define NUM_EDGES 100000
#define NNZ       1600000
#define D         64

#define BKT     128                          // targets per bucket
#define NBKT_E  ((NUM_EDGES + BKT - 1) / BKT)   // 782
#define NBKT_V  ((NUM_NODES + BKT - 1) / BKT)   // 782
#define NBKT_TOT (NBKT_E + NBKT_V)              // 1564
#define CAP     2816                         // padded words per bucket segment

#define TILE 8192                            // entries per bin tile
#define NT_SIDE ((NNZ + TILE - 1) / TILE)    // 196 tiles per side

#define GEMM_ROWS 32
#define NGEMM (NUM_NODES / GEMM_ROWS)        // 3125

#define CK_SHIFT 14                          // 16384-row chunks (2 MB bf16 rows)
#define NCHUNK   8                           // covers ids < 131072

// ---- bf16 helpers (RNE pack, shift unpack) --------------------------------
__device__ inline unsigned pack_bf16x2(float a, float b) {
  unsigned ua = __float_as_uint(a), ub = __float_as_uint(b);
  ua = (ua + 0x7fffu + ((ua >> 16) & 1u)) >> 16;
  ub = (ub + 0x7fffu + ((ub >> 16) & 1u)) >> 16;
  return ua | (ub << 16);
}
__device__ inline void unpack_acc(unsigned u, float& lo, float& hi) {
  lo = __uint_as_float(u << 16);
  hi = __uint_as_float(u & 0xffff0000u);
}
__device__ inline void acc_row(const uint4& w, float* acc) {
  float lo, hi;
  unpack_acc(w.x, lo, hi); acc[0] += lo; acc[1] += hi;
  unpack_acc(w.y, lo, hi); acc[2] += lo; acc[3] += hi;
  unpack_acc(w.z, lo, hi); acc[4] += lo; acc[5] += hi;
  unpack_acc(w.w, lo, hi); acc[6] += lo; acc[7] += hi;
}

// ---------------------------------------------------------------------------
// Kernel 1: tile-local counting sort + bulk-reserved contiguous write-out.
// Round-6 form (register-staged V/E, shfl scan, direct bucket lookup).
// curb is ZERO-BASED (memset by host): dest = b*CAP + reserved - excl + sI.
// ---------------------------------------------------------------------------
__global__ __launch_bounds__(1024, 4) void bin_tile_k(
    const int* __restrict__ V, const int* __restrict__ E,
    int* __restrict__ curb, unsigned* __restrict__ pair) {
  __shared__ unsigned stage[TILE];            // 32 KB
  __shared__ unsigned short stageb[TILE];     // 16 KB (bucket id per slot)
  __shared__ int hist[NBKT_E];                // per-bucket counts
  __shared__ int gbase[NBKT_E];               // folded dest base
  __shared__ int lcur[NBKT_E];                // running local cursor
  __shared__ int wsum[16];                    // per-wave scan totals

  const int t = threadIdx.x;
  const int side = (blockIdx.x >= NT_SIDE) ? 1 : 0;
  const int bt = blockIdx.x - side * NT_SIDE;
  const int j0 = bt * TILE;
  const int n = (NNZ - j0 < TILE) ? (NNZ - j0) : TILE;
  const int cbase = side ? NBKT_E : 0;

  for (int i = t; i < NBKT_E; i += 1024) hist[i] = 0;
  __syncthreads();

  // phase 1: single global read of V,E into registers; LDS histogram
  int vj[8], ej[8];
#pragma unroll
  for (int k = 0; k < 8; ++k) {
    const int jj = t + k * 1024;
    int v = -1, e = 0;
    if (jj < n) {
      v = V[j0 + jj];
      e = E[j0 + jj];
    }
    vj[k] = v; ej[k] = e;
    if (v >= 0) atomicAdd(&hist[(side ? v : e) >> 7], 1);
  }
  __syncthreads();

  // phase 2: shfl wave-scan over 782 counts + one global reservation/bucket
  {
    const int lane = t & 63, wid = t >> 6;
    const int cb = (t < NBKT_E) ? hist[t] : 0;
    int s = cb;
#pragma unroll
    for (int d = 1; d < 64; d <<= 1) {
      const int y = __shfl_up(s, d, 64);
      if (lane >= d) s += y;
    }
    if (lane == 63) wsum[wid] = s;
    __syncthreads();
    if (wid == 0) {
      int ws = (lane < 16) ? wsum[lane] : 0;
#pragma unroll
      for (int d = 1; d < 16; d <<= 1) {
        const int y = __shfl_up(ws, d, 64);
        if (lane >= d) ws += y;
      }
      if (lane < 16) wsum[lane] = ws;
    }
    __syncthreads();
    const int incl = s + (wid > 0 ? wsum[wid - 1] : 0);
    if (t < NBKT_E) {
      const int excl = incl - cb;               // exclusive local offset
      lcur[t] = excl;
      const int rb = cb ? atomicAdd(&curb[cbase + t], cb) : 0;
      gbase[t] = (cbase + t) * CAP + rb - excl;  // dest = gbase[b] + sI
    }
  }
  __syncthreads();

  // phase 3: local bucket-sort into stage (from registers); record bucket id
#pragma unroll
  for (int k = 0; k < 8; ++k) {
    const int v = vj[k];
    if (v >= 0) {
      const int e = ej[k];
      const int key = side ? v : e;
      const int src = side ? e : v;
      const int b = key >> 7;
      const unsigned w = ((unsigned)src << 7) | (unsigned)(key & 127);
      const int pos = atomicAdd(&lcur[b], 1);
      stage[pos] = w;
      stageb[pos] = (unsigned short)b;
    }
  }
  __syncthreads();

  // phase 4: dense write-out; direct bucket lookup (no binary search)
  for (int sI = t; sI < n; sI += 1024) {
    pair[gbase[stageb[sI]] + sI] = stage[sI];
  }
}

// ---------------------------------------------------------------------------
// Kernel 2: HETEROGENEOUS deg + gemm (independent work, one launch).
// Round-5 verified, unchanged.
// ---------------------------------------------------------------------------
#define DG_SMEM 24832   // max(deg 512 B, gemm Wl 16640 + Xl 8192)
__global__ __launch_bounds__(256) void deg_gemm_k(
    const int* __restrict__ curb, const unsigned* __restrict__ pair,
    int* __restrict__ cnt_v,
    const float* __restrict__ X, const float* __restrict__ W,
    const float* __restrict__ bvec, unsigned short* __restrict__ Xpb) {
  __shared__ __align__(16) char smem[DG_SMEM];
  const int t = threadIdx.x;

  if (blockIdx.x < NBKT_V) {
    // ---- deg path ----
    int* rcnt = (int*)smem;
    const int b = blockIdx.x;
    const int base = (NBKT_E + b) * CAP;
    int n = curb[NBKT_E + b];                 // zero-based count
    if (n > CAP) n = CAP;
    if (t < BKT) rcnt[t] = 0;
    __syncthreads();
    for (int j = t; j < n; j += 256) {
      atomicAdd(&rcnt[pair[base + j] & 127u], 1);
    }
    __syncthreads();
    const int v = b * BKT + t;
    if (t < BKT && v < NUM_NODES) cnt_v[v] = rcnt[t];
  } else {
    // ---- gemm path (round-0 proven form) ----
    float* Wl = (float*)smem;                 // [64][65]
    float* Xl = (float*)(smem + 16640);       // [32][64]
    const int g = blockIdx.x - NBKT_V;

    for (int j = t; j < D * D; j += 256) Wl[(j >> 6) * 65 + (j & 63)] = W[j];
    const int row0 = g * GEMM_ROWS;
    const float4* X4 = (const float4*)(X + (size_t)row0 * D);
    float4* Xl4 = (float4*)Xl;
    for (int j = t; j < GEMM_ROWS * (D / 4); j += 256) Xl4[j] = X4[j];
    __syncthreads();

    const int c = t & 63;
    const int rq = t >> 6;
    float acc[8];
#pragma unroll
    for (int i = 0; i < 8; ++i) acc[i] = 0.f;
#pragma unroll
    for (int k = 0; k < D; ++k) {
      const float w = Wl[c * 65 + k];
#pragma unroll
      for (int i = 0; i < 8; ++i)
        acc[i] = fmaf(Xl[(rq + i * 4) * D + k], w, acc[i]);
    }
    const float bias = bvec[c];
#pragma unroll
    for (int i = 0; i < 8; ++i) {
      const int r = row0 + rq + i * 4;
      const float v = acc[i] + bias;
      unsigned u = __float_as_uint(v);
      u = (u + 0x7fffu + ((u >> 16) & 1u)) >> 16;
      Xpb[(size_t)r * D + c] = (unsigned short)u;
    }
  }
}

// ---------------------------------------------------------------------------
// Kernel 3: FUSED edge pass. One block = one edge bucket (128 edges).
// Delta vs round-6: member loop iterated in 8 node-id CHUNKS of 16K rows
// (2 MB of Xpb) so the gather working set is L2-resident per chunk.
// Rank-order (round-7) reverted.
// ---------------------------------------------------------------------------
__global__ __launch_bounds__(512) void edge_fused_k(
    const int* __restrict__ curb, const unsigned* __restrict__ pair,
    const int* __restrict__ cnt_v, const uint4* __restrict__ Xpb,
    uint4* __restrict__ Yb) {
  __shared__ unsigned seg[CAP];
  __shared__ int sorted_[CAP];
  __shared__ int rcnt[BKT];
  __shared__ int sc[BKT];
  __shared__ int lcur[BKT];
  const int b = blockIdx.x, t = threadIdx.x;
  const int base = b * CAP;
  int n = curb[b];
  if (n > CAP) n = CAP;
  const int e0 = b * BKT;
  const int nrows = (NUM_EDGES - e0 < BKT) ? (NUM_EDGES - e0) : BKT;

  if (t < BKT) rcnt[t] = 0;
  __syncthreads();

  for (int j = t; j < n; j += 512) {
    const unsigned w = pair[base + j];
    seg[j] = w;
    atomicAdd(&rcnt[w & 127u], 1);
  }
  __syncthreads();

  // single-wave shfl scan of 128 row counts (2 rows per lane)
  if (t < 64) {
    const int a = rcnt[2 * t], bb = rcnt[2 * t + 1];
    int s = a + bb;
#pragma unroll
    for (int d = 1; d < 64; d <<= 1) {
      const int y = __shfl_up(s, d, 64);
      if (t >= d) s += y;
    }
    sc[2 * t + 1] = s;
    sc[2 * t] = s - bb;
    lcur[2 * t + 1] = s - bb;
    lcur[2 * t] = s - bb - a;
  }
  __syncthreads();

  // row-sort member ids into LDS
  for (int j = t; j < n; j += 512) {
    const unsigned w = seg[j];
    const int pos = atomicAdd(&lcur[w & 127u], 1);
    sorted_[pos] = (int)(w >> 7);
  }
  __syncthreads();

  // gather: 8 lanes per row, 64 rows per pass, 2 passes; 8 id-chunks
  const int q = t & 7;
#pragma unroll
  for (int rr = 0; rr < 2; ++rr) {
    const int row = (t >> 3) + rr * 64;
    const int ne = rcnt[row];
    const int mb = sc[row] - ne;
    const int me = sc[row];
    float acc[8];
#pragma unroll
    for (int i = 0; i < 8; ++i) acc[i] = 0.f;
    float dsum = 0.f;
    for (int ck = 0; ck < NCHUNK; ++ck) {
      for (int m = mb; m < me; ++m) {
        const int v = sorted_[m];                 // LDS broadcast (8 lanes)
        if ((v >> CK_SHIFT) == ck) {
          const uint4 w = Xpb[v * 8 + q];
          dsum += (float)cnt_v[v];
          acc_row(w, acc);
        }
      }
    }
    const float ce = (float)ne;
    const float De = dsum / (ce + 1.f);
    const float inv = (De > 0.f) ? rsqrtf(fmaxf(De, 1e-30f)) : 1.f;
    const float s = inv / fmaxf(ce, 1.f);
    if (row < nrows) {
      uint4 o;
      o.x = pack_bf16x2(acc[0] * s, acc[1] * s);
      o.y = pack_bf16x2(acc[2] * s, acc[3] * s);
      o.z = pack_bf16x2(acc[4] * s, acc[5] * s);
      o.w = pack_bf16x2(acc[6] * s, acc[7] * s);
      Yb[(e0 + row) * 8 + q] = o;
    }
  }
}

// ---------------------------------------------------------------------------
// Kernel 4: FUSED node pass. One block = one node bucket (128 nodes).
// Delta vs round-6: 8 edge-id chunks (2 MB of Yb L2-resident per chunk).
// ---------------------------------------------------------------------------
__global__ __launch_bounds__(512) void node_fused_k(
    const int* __restrict__ curb, const unsigned* __restrict__ pair,
    const uint4* __restrict__ Yb, float* __restrict__ Out) {
  __shared__ unsigned seg[CAP];
  __shared__ int sorted_[CAP];
  __shared__ int rcnt[BKT];
  __shared__ int sc[BKT];
  __shared__ int lcur[BKT];
  const int b = blockIdx.x, t = threadIdx.x;
  const int base = (NBKT_E + b) * CAP;
  int n = curb[NBKT_E + b];
  if (n > CAP) n = CAP;
  const int v0r = b * BKT;
  const int nrows = (NUM_NODES - v0r < BKT) ? (NUM_NODES - v0r) : BKT;

  if (t < BKT) rcnt[t] = 0;
  __syncthreads();

  for (int j = t; j < n; j += 512) {
    const unsigned w = pair[base + j];
    seg[j] = w;
    atomicAdd(&rcnt[w & 127u], 1);
  }
  __syncthreads();

  if (t < 64) {
    const int a = rcnt[2 * t], bb = rcnt[2 * t + 1];
    int s = a + bb;
#pragma unroll
    for (int d = 1; d < 64; d <<= 1) {
      const int y = __shfl_up(s, d, 64);
      if (t >= d) s += y;
    }
    sc[2 * t + 1] = s;
    sc[2 * t] = s - bb;
    lcur[2 * t + 1] = s - bb;
    lcur[2 * t] = s - bb - a;
  }
  __syncthreads();

  for (int j = t; j < n; j += 512) {
    const unsigned w = seg[j];
    const int pos = atomicAdd(&lcur[w & 127u], 1);
    sorted_[pos] = (int)(w >> 7);
  }
  __syncthreads();

  const int q = t & 7;
#pragma unroll
  for (int rr = 0; rr < 2; ++rr) {
    const int row = (t >> 3) + rr * 64;
    const int dv = rcnt[row];
    const int mb = sc[row] - dv;
    const int me = sc[row];
    float acc[8];
#pragma unroll
    for (int i = 0; i < 8; ++i) acc[i] = 0.f;
    for (int ck = 0; ck < NCHUNK; ++ck) {
      for (int m = mb; m < me; ++m) {
        const int e = sorted_[m];                 // LDS broadcast (8 lanes)
        if ((e >> CK_SHIFT) == ck) {
          acc_row(Yb[e * 8 + q], acc);
        }
      }
    }
    const float d = (float)dv;
    const float s = (d > 0.f) ? rsqrtf(d) : 0.f;
    if (row < nrows) {
      float4* O4 = (float4*)(Out + (size_t)(v0r + row) * D + q * 8);
      O4[0] = make_float4(acc[0] * s, acc[1] * s, acc[2] * s, acc[3] * s);
      O4[1] = make_float4(acc[4] * s, acc[5] * s, acc[6] * s, acc[7] * s);
    }
  }
}

extern "C" void kernel_launch(void* const* d_in, const int* in_sizes, int n_in,
                              void* d_out, int out_size, void* d_ws, size_t ws_size,
                              hipStream_t stream) {
  const float* X = (const float*)d_in[0];
  const int*   V = (const int*)d_in[1];
  const int*   E = (const int*)d_in[2];
  const float* W = (const float*)d_in[4];
  const float* b = (const float*)d_in[5];
  float* Out = (float*)d_out;

  // workspace layout (~44 MB)
  unsigned short* Xpb = (unsigned short*)d_ws;                 // 12.8 MB bf16
  unsigned short* Ybu = Xpb + (size_t)NUM_NODES * D;           // 12.8 MB bf16
  int*      curb   = (int*)(Ybu + (size_t)NUM_EDGES * D);      // 1564 (zero-based)
  int*      cnt_v  = curb + NBKT_TOT;                          // 400 KB
  unsigned* pair   = (unsigned*)(cnt_v + NUM_NODES);           // 17.6 MB

  hipMemsetAsync(curb, 0, NBKT_TOT * sizeof(int), stream);
  bin_tile_k<<<2 * NT_SIDE, 1024, 0, stream>>>(V, E, curb, pair);
  deg_gemm_k<<<NBKT_V + NGEMM, 256, 0, stream>>>(
      curb, pair, cnt_v, X, W, b, Xpb);
  edge_fused_k<<<NBKT_E, 512, 0, stream>>>(
      curb, pair, cnt_v, (const uint4*)Xpb, (uint4*)Ybu);
  node_fused_k<<<NBKT_V, 512, 0, stream>>>(
      curb, pair, (const uint4*)Ybu, Out);
}

// Round 9
// 199.841 us; speedup vs baseline: 1.6535x; 1.6535x over previous
//
#include <hip/hip_runtime.h>
#include <hip/hip_bf16.h>

#define NUM_NODES 100000
#define NUM_EDGES 100000
#define NNZ       1600000
#define D         64

#define BKT     128                          // targets per bucket
#define NBKT_E  ((NUM_EDGES + BKT - 1) / BKT)   // 782
#define NBKT_V  ((NUM_NODES + BKT - 1) / BKT)   // 782
#define NBKT_TOT (NBKT_E + NBKT_V)              // 1564
#define CAP     2816                         // padded words per bucket segment

#define TILE 8192                            // entries per bin tile
#define NT_SIDE ((NNZ + TILE - 1) / TILE)    // 196 tiles per side

#define GEMM_ROWS 32
#define NGEMM (NUM_NODES / GEMM_ROWS)        // 3125

// ---- bf16 helpers (RNE pack, shift unpack) --------------------------------
__device__ inline unsigned pack_bf16x2(float a, float b) {
  unsigned ua = __float_as_uint(a), ub = __float_as_uint(b);
  ua = (ua + 0x7fffu + ((ua >> 16) & 1u)) >> 16;
  ub = (ub + 0x7fffu + ((ub >> 16) & 1u)) >> 16;
  return ua | (ub << 16);
}
__device__ inline void unpack_acc(unsigned u, float& lo, float& hi) {
  lo = __uint_as_float(u << 16);
  hi = __uint_as_float(u & 0xffff0000u);
}
__device__ inline void acc_row(const uint4& w, float* acc) {
  float lo, hi;
  unpack_acc(w.x, lo, hi); acc[0] += lo; acc[1] += hi;
  unpack_acc(w.y, lo, hi); acc[2] += lo; acc[3] += hi;
  unpack_acc(w.z, lo, hi); acc[4] += lo; acc[5] += hi;
  unpack_acc(w.w, lo, hi); acc[6] += lo; acc[7] += hi;
}

// ---------------------------------------------------------------------------
// Kernel 1: tile-local counting sort + bulk-reserved contiguous write-out.
// Round-5 verbatim (193.7 µs proven). curb ZERO-BASED (memset by host):
// dest = b*CAP + reserved - excl + sI.
// ---------------------------------------------------------------------------
__global__ __launch_bounds__(1024, 4) void bin_tile_k(
    const int* __restrict__ V, const int* __restrict__ E,
    int* __restrict__ curb, unsigned* __restrict__ pair) {
  __shared__ unsigned stage[TILE];            // 32 KB
  __shared__ unsigned short stageb[TILE];     // 16 KB (bucket id per slot)
  __shared__ int hist[NBKT_E];
  __shared__ int gbase[NBKT_E];
  __shared__ int lcur[NBKT_E];
  __shared__ int wsum[16];

  const int t = threadIdx.x;
  const int side = (blockIdx.x >= NT_SIDE) ? 1 : 0;
  const int bt = blockIdx.x - side * NT_SIDE;
  const int j0 = bt * TILE;
  const int n = (NNZ - j0 < TILE) ? (NNZ - j0) : TILE;
  const int cbase = side ? NBKT_E : 0;

  for (int i = t; i < NBKT_E; i += 1024) hist[i] = 0;
  __syncthreads();

  // phase 1: tile histogram (LDS atomics only)
#pragma unroll
  for (int k = 0; k < TILE / 1024; ++k) {
    const int j = j0 + t + k * 1024;
    if (j - j0 < n) {
      const int key = side ? V[j] : E[j];
      atomicAdd(&hist[key >> 7], 1);
    }
  }
  __syncthreads();

  // phase 2: shfl wave-scan over 782 counts + one global reservation/bucket
  {
    const int lane = t & 63, wid = t >> 6;
    const int cb = (t < NBKT_E) ? hist[t] : 0;
    int s = cb;
#pragma unroll
    for (int d = 1; d < 64; d <<= 1) {
      const int y = __shfl_up(s, d, 64);
      if (lane >= d) s += y;
    }
    if (lane == 63) wsum[wid] = s;
    __syncthreads();
    if (wid == 0) {
      int ws = (lane < 16) ? wsum[lane] : 0;
#pragma unroll
      for (int d = 1; d < 16; d <<= 1) {
        const int y = __shfl_up(ws, d, 64);
        if (lane >= d) ws += y;
      }
      if (lane < 16) wsum[lane] = ws;
    }
    __syncthreads();
    const int incl = s + (wid > 0 ? wsum[wid - 1] : 0);
    if (t < NBKT_E) {
      const int excl = incl - cb;
      lcur[t] = excl;
      const int rb = cb ? atomicAdd(&curb[cbase + t], cb) : 0;
      gbase[t] = (cbase + t) * CAP + rb - excl;
    }
  }
  __syncthreads();

  // phase 3: local bucket-sort into stage; record bucket id per slot
#pragma unroll
  for (int k = 0; k < TILE / 1024; ++k) {
    const int j = j0 + t + k * 1024;
    if (j - j0 < n) {
      const int v = V[j], e = E[j];
      const int key = side ? v : e;
      const int src = side ? e : v;
      const int b = key >> 7;
      const unsigned w = ((unsigned)src << 7) | (unsigned)(key & 127);
      const int pos = atomicAdd(&lcur[b], 1);
      stage[pos] = w;
      stageb[pos] = (unsigned short)b;
    }
  }
  __syncthreads();

  // phase 4: dense write-out; direct bucket lookup
  for (int sI = t; sI < n; sI += 1024) {
    pair[gbase[stageb[sI]] + sI] = stage[sI];
  }
}

// ---------------------------------------------------------------------------
// Kernel 2: HETEROGENEOUS stage + gemm.
// Blocks [0, NBKT_TOT): per-bucket row-sort of `pair` segment IN-PLACE
// (sorted member ids replace packed words; block owns its segment), row
// offsets (inclusive prefix) to soff[b][0..127]; node buckets also emit
// cnt_v (the stage histogram IS the degree count -> deg pass absorbed).
// Blocks [NBKT_TOT, +NGEMM): Xp = bf16(X @ W^T + b) (round-0 proven form).
// ---------------------------------------------------------------------------
#define SG_SMEM 24832   // max(stage 24064, gemm 16640+8192)
__global__ __launch_bounds__(256) void stage_gemm_k(
    const int* __restrict__ curb, unsigned* __restrict__ pair,
    int* __restrict__ soff, int* __restrict__ cnt_v,
    const float* __restrict__ X, const float* __restrict__ W,
    const float* __restrict__ bvec, unsigned short* __restrict__ Xpb) {
  __shared__ __align__(16) char smem[SG_SMEM];
  const int t = threadIdx.x;

  if (blockIdx.x < NBKT_TOT) {
    // ---- stage path ----
    unsigned* seg = (unsigned*)smem;              // 11264 B
    int* sorted_ = (int*)(smem + 11264);          // 11264 B
    int* rcnt = (int*)(smem + 22528);             // 512 B
    int* sc   = (int*)(smem + 23040);             // 512 B
    int* lcur = (int*)(smem + 23552);             // 512 B
    const int b = blockIdx.x;
    const int base = b * CAP;
    int n = curb[b];
    if (n > CAP) n = CAP;

    if (t < BKT) rcnt[t] = 0;
    __syncthreads();

    for (int j = t; j < n; j += 256) {
      const unsigned w = pair[base + j];
      seg[j] = w;
      atomicAdd(&rcnt[w & 127u], 1);
    }
    __syncthreads();

    // single-wave shfl scan of 128 row counts (2 rows per lane)
    if (t < 64) {
      const int a = rcnt[2 * t], bb = rcnt[2 * t + 1];
      int s = a + bb;
#pragma unroll
      for (int d = 1; d < 64; d <<= 1) {
        const int y = __shfl_up(s, d, 64);
        if (t >= d) s += y;
      }
      sc[2 * t + 1] = s;
      sc[2 * t] = s - bb;
      lcur[2 * t + 1] = s - bb;
      lcur[2 * t] = s - bb - a;
    }
    __syncthreads();

    // row-sort member ids into LDS
    for (int j = t; j < n; j += 256) {
      const unsigned w = seg[j];
      const int pos = atomicAdd(&lcur[w & 127u], 1);
      sorted_[pos] = (int)(w >> 7);
    }
    __syncthreads();

    // write sorted ids back IN-PLACE (coalesced) + offsets (+ degrees)
    for (int j = t; j < n; j += 256) pair[base + j] = (unsigned)sorted_[j];
    if (t < BKT) {
      soff[b * BKT + t] = sc[t];                  // inclusive prefix
      if (b >= NBKT_E) {
        const int v = (b - NBKT_E) * BKT + t;
        if (v < NUM_NODES) cnt_v[v] = rcnt[t];
      }
    }
  } else {
    // ---- gemm path (round-0 proven form) ----
    float* Wl = (float*)smem;                 // [64][65]
    float* Xl = (float*)(smem + 16640);       // [32][64]
    const int g = blockIdx.x - NBKT_TOT;

    for (int j = t; j < D * D; j += 256) Wl[(j >> 6) * 65 + (j & 63)] = W[j];
    const int row0 = g * GEMM_ROWS;
    const float4* X4 = (const float4*)(X + (size_t)row0 * D);
    float4* Xl4 = (float4*)Xl;
    for (int j = t; j < GEMM_ROWS * (D / 4); j += 256) Xl4[j] = X4[j];
    __syncthreads();

    const int c = t & 63;
    const int rq = t >> 6;
    float acc[8];
#pragma unroll
    for (int i = 0; i < 8; ++i) acc[i] = 0.f;
#pragma unroll
    for (int k = 0; k < D; ++k) {
      const float w = Wl[c * 65 + k];
#pragma unroll
      for (int i = 0; i < 8; ++i)
        acc[i] = fmaf(Xl[(rq + i * 4) * D + k], w, acc[i]);
    }
    const float bias = bvec[c];
#pragma unroll
    for (int i = 0; i < 8; ++i) {
      const int r = row0 + rq + i * 4;
      const float v = acc[i] + bias;
      unsigned u = __float_as_uint(v);
      u = (u + 0x7fffu + ((u >> 16) & 1u)) >> 16;
      Xpb[(size_t)r * D + c] = (unsigned short)u;
    }
  }
}

// ---------------------------------------------------------------------------
// Kernel 3: edge gather (pure). One block = one edge bucket (128 edges).
// No staging: read 128 offsets, gather sorted member ids from pair (global,
// broadcast-coalesced), accumulate, normalize, write bf16 Y.
// ---------------------------------------------------------------------------
__global__ __launch_bounds__(512) void edge_gather_k(
    const unsigned* __restrict__ pair, const int* __restrict__ soff,
    const int* __restrict__ cnt_v, const uint4* __restrict__ Xpb,
    uint4* __restrict__ Yb) {
  __shared__ int sc[BKT];
  const int b = blockIdx.x, t = threadIdx.x;
  const int base = b * CAP;
  const int e0 = b * BKT;
  const int nrows = (NUM_EDGES - e0 < BKT) ? (NUM_EDGES - e0) : BKT;

  if (t < BKT) sc[t] = soff[b * BKT + t];
  __syncthreads();

  const int q = t & 7;
#pragma unroll
  for (int rr = 0; rr < 2; ++rr) {
    const int row = (t >> 3) + rr * 64;
    const int me = sc[row];
    const int mb = (row > 0) ? sc[row - 1] : 0;
    const int ne = me - mb;
    float acc[8];
#pragma unroll
    for (int i = 0; i < 8; ++i) acc[i] = 0.f;
    float dsum = 0.f;
    int m = mb;
    for (; m + 3 < me; m += 4) {
      int vv[4];
#pragma unroll
      for (int i = 0; i < 4; ++i) vv[i] = (int)pair[base + m + i];
      uint4 w[4];
#pragma unroll
      for (int i = 0; i < 4; ++i) w[i] = Xpb[vv[i] * 8 + q];
      float dd[4];
#pragma unroll
      for (int i = 0; i < 4; ++i) dd[i] = (float)cnt_v[vv[i]];
      dsum += (dd[0] + dd[1]) + (dd[2] + dd[3]);
#pragma unroll
      for (int i = 0; i < 4; ++i) acc_row(w[i], acc);
    }
    for (; m < me; ++m) {
      const int v = (int)pair[base + m];
      const uint4 w = Xpb[v * 8 + q];
      dsum += (float)cnt_v[v];
      acc_row(w, acc);
    }
    const float ce = (float)ne;
    const float De = dsum / (ce + 1.f);
    const float inv = (De > 0.f) ? rsqrtf(fmaxf(De, 1e-30f)) : 1.f;
    const float s = inv / fmaxf(ce, 1.f);
    if (row < nrows) {
      uint4 o;
      o.x = pack_bf16x2(acc[0] * s, acc[1] * s);
      o.y = pack_bf16x2(acc[2] * s, acc[3] * s);
      o.z = pack_bf16x2(acc[4] * s, acc[5] * s);
      o.w = pack_bf16x2(acc[6] * s, acc[7] * s);
      Yb[(e0 + row) * 8 + q] = o;
    }
  }
}

// ---------------------------------------------------------------------------
// Kernel 4: node gather (pure). One block = one node bucket (128 nodes).
// ---------------------------------------------------------------------------
__global__ __launch_bounds__(512) void node_gather_k(
    const unsigned* __restrict__ pair, const int* __restrict__ soff,
    const uint4* __restrict__ Yb, float* __restrict__ Out) {
  __shared__ int sc[BKT];
  const int b = blockIdx.x, t = threadIdx.x;
  const int base = (NBKT_E + b) * CAP;
  const int v0r = b * BKT;
  const int nrows = (NUM_NODES - v0r < BKT) ? (NUM_NODES - v0r) : BKT;

  if (t < BKT) sc[t] = soff[(NBKT_E + b) * BKT + t];
  __syncthreads();

  const int q = t & 7;
#pragma unroll
  for (int rr = 0; rr < 2; ++rr) {
    const int row = (t >> 3) + rr * 64;
    const int me = sc[row];
    const int mb = (row > 0) ? sc[row - 1] : 0;
    const int dv = me - mb;
    float acc[8];
#pragma unroll
    for (int i = 0; i < 8; ++i) acc[i] = 0.f;
    int m = mb;
    for (; m + 3 < me; m += 4) {
      int ee[4];
#pragma unroll
      for (int i = 0; i < 4; ++i) ee[i] = (int)pair[base + m + i];
      uint4 w[4];
#pragma unroll
      for (int i = 0; i < 4; ++i) w[i] = Yb[ee[i] * 8 + q];
#pragma unroll
      for (int i = 0; i < 4; ++i) acc_row(w[i], acc);
    }
    for (; m < me; ++m) {
      acc_row(Yb[(int)pair[base + m] * 8 + q], acc);
    }
    const float d = (float)dv;
    const float s = (d > 0.f) ? rsqrtf(d) : 0.f;
    if (row < nrows) {
      float4* O4 = (float4*)(Out + (size_t)(v0r + row) * D + q * 8);
      O4[0] = make_float4(acc[0] * s, acc[1] * s, acc[2] * s, acc[3] * s);
      O4[1] = make_float4(acc[4] * s, acc[5] * s, acc[6] * s, acc[7] * s);
    }
  }
}

extern "C" void kernel_launch(void* const* d_in, const int* in_sizes, int n_in,
                              void* d_out, int out_size, void* d_ws, size_t ws_size,
                              hipStream_t stream) {
  const float* X = (const float*)d_in[0];
  const int*   V = (const int*)d_in[1];
  const int*   E = (const int*)d_in[2];
  const float* W = (const float*)d_in[4];
  const float* b = (const float*)d_in[5];
  float* Out = (float*)d_out;

  // workspace layout (~45 MB)
  unsigned short* Xpb = (unsigned short*)d_ws;                 // 12.8 MB bf16
  unsigned short* Ybu = Xpb + (size_t)NUM_NODES * D;           // 12.8 MB bf16
  int*      curb   = (int*)(Ybu + (size_t)NUM_EDGES * D);      // 1564 (zero-based)
  int*      cnt_v  = curb + NBKT_TOT;                          // 400 KB
  int*      soff   = cnt_v + NUM_NODES;                        // 800 KB
  unsigned* pair   = (unsigned*)(soff + NBKT_TOT * BKT);       // 17.6 MB

  hipMemsetAsync(curb, 0, NBKT_TOT * sizeof(int), stream);
  bin_tile_k<<<2 * NT_SIDE, 1024, 0, stream>>>(V, E, curb, pair);
  stage_gemm_k<<<NBKT_TOT + NGEMM, 256, 0, stream>>>(
      curb, pair, soff, cnt_v, X, W, b, Xpb);
  edge_gather_k<<<NBKT_E, 512, 0, stream>>>(
      pair, soff, cnt_v, (const uint4*)Xpb, (uint4*)Ybu);
  node_gather_k<<<NBKT_V, 512, 0, stream>>>(
      pair, soff, (const uint4*)Ybu, Out);
}

// Round 10
// 192.501 us; speedup vs baseline: 1.7166x; 1.0381x over previous
//
#include <hip/hip_runtime.h>
#include <hip/hip_bf16.h>

#define NUM_NODES 100000
#define NUM_EDGES 100000
#define NNZ       1600000
#define D         64

#define BKT     128                          // targets per bucket
#define NBKT_E  ((NUM_EDGES + BKT - 1) / BKT)   // 782
#define NBKT_V  ((NUM_NODES + BKT - 1) / BKT)   // 782
#define NBKT_TOT (NBKT_E + NBKT_V)              // 1564
#define CAP     2816                         // padded words per bucket segment

#define TILE 8192                            // entries per bin tile
#define NT_SIDE ((NNZ + TILE - 1) / TILE)    // 196 tiles per side

#define GEMM_ROWS 32
#define NGEMM (NUM_NODES / GEMM_ROWS)        // 3125

// ---- bf16 helpers (RNE pack, shift unpack) --------------------------------
__device__ inline unsigned pack_bf16x2(float a, float b) {
  unsigned ua = __float_as_uint(a), ub = __float_as_uint(b);
  ua = (ua + 0x7fffu + ((ua >> 16) & 1u)) >> 16;
  ub = (ub + 0x7fffu + ((ub >> 16) & 1u)) >> 16;
  return ua | (ub << 16);
}
__device__ inline void unpack_acc(unsigned u, float& lo, float& hi) {
  lo = __uint_as_float(u << 16);
  hi = __uint_as_float(u & 0xffff0000u);
}
__device__ inline void acc_row(const uint4& w, float* acc) {
  float lo, hi;
  unpack_acc(w.x, lo, hi); acc[0] += lo; acc[1] += hi;
  unpack_acc(w.y, lo, hi); acc[2] += lo; acc[3] += hi;
  unpack_acc(w.z, lo, hi); acc[4] += lo; acc[5] += hi;
  unpack_acc(w.w, lo, hi); acc[6] += lo; acc[7] += hi;
}

// ---------------------------------------------------------------------------
// Kernel 1: tile-local counting sort + bulk-reserved contiguous write-out.
// curb is ZERO-BASED (memset by host): dest = b*CAP + reserved - excl + sI.
// ---------------------------------------------------------------------------
__global__ __launch_bounds__(1024, 4) void bin_tile_k(
    const int* __restrict__ V, const int* __restrict__ E,
    int* __restrict__ curb, unsigned* __restrict__ pair) {
  __shared__ unsigned stage[TILE];            // 32 KB
  __shared__ unsigned short stageb[TILE];     // 16 KB (bucket id per slot)
  __shared__ int hist[NBKT_E];                // per-bucket counts
  __shared__ int gbase[NBKT_E];               // folded dest base
  __shared__ int lcur[NBKT_E];                // running local cursor
  __shared__ int wsum[16];                    // per-wave scan totals

  const int t = threadIdx.x;
  const int side = (blockIdx.x >= NT_SIDE) ? 1 : 0;
  const int bt = blockIdx.x - side * NT_SIDE;
  const int j0 = bt * TILE;
  const int n = (NNZ - j0 < TILE) ? (NNZ - j0) : TILE;
  const int cbase = side ? NBKT_E : 0;

  for (int i = t; i < NBKT_E; i += 1024) hist[i] = 0;
  __syncthreads();

  // phase 1: tile histogram (LDS atomics only)
#pragma unroll
  for (int k = 0; k < TILE / 1024; ++k) {
    const int j = j0 + t + k * 1024;
    if (j - j0 < n) {
      const int key = side ? V[j] : E[j];
      atomicAdd(&hist[key >> 7], 1);
    }
  }
  __syncthreads();

  // phase 2: shfl wave-scan over 782 counts + one global reservation/bucket
  {
    const int lane = t & 63, wid = t >> 6;
    const int cb = (t < NBKT_E) ? hist[t] : 0;
    int s = cb;
#pragma unroll
    for (int d = 1; d < 64; d <<= 1) {
      const int y = __shfl_up(s, d, 64);
      if (lane >= d) s += y;
    }
    if (lane == 63) wsum[wid] = s;
    __syncthreads();
    if (wid == 0) {
      int ws = (lane < 16) ? wsum[lane] : 0;
#pragma unroll
      for (int d = 1; d < 16; d <<= 1) {
        const int y = __shfl_up(ws, d, 64);
        if (lane >= d) ws += y;
      }
      if (lane < 16) wsum[lane] = ws;
    }
    __syncthreads();
    const int incl = s + (wid > 0 ? wsum[wid - 1] : 0);
    if (t < NBKT_E) {
      const int excl = incl - cb;               // exclusive local offset
      lcur[t] = excl;
      const int rb = cb ? atomicAdd(&curb[cbase + t], cb) : 0;
      gbase[t] = (cbase + t) * CAP + rb - excl;  // dest = gbase[b] + sI
    }
  }
  __syncthreads();

  // phase 3: local bucket-sort into stage; record bucket id per slot
#pragma unroll
  for (int k = 0; k < TILE / 1024; ++k) {
    const int j = j0 + t + k * 1024;
    if (j - j0 < n) {
      const int v = V[j], e = E[j];
      const int key = side ? v : e;
      const int src = side ? e : v;
      const int b = key >> 7;
      const unsigned w = ((unsigned)src << 7) | (unsigned)(key & 127);
      const int pos = atomicAdd(&lcur[b], 1);
      stage[pos] = w;
      stageb[pos] = (unsigned short)b;
    }
  }
  __syncthreads();

  // phase 4: dense write-out; direct bucket lookup (no binary search)
  for (int sI = t; sI < n; sI += 1024) {
    pair[gbase[stageb[sI]] + sI] = stage[sI];
  }
}

// ---------------------------------------------------------------------------
// Kernel 2: HETEROGENEOUS deg + gemm (independent work, one launch).
// ---------------------------------------------------------------------------
#define DG_SMEM 24832   // max(deg 512 B, gemm Wl 16640 + Xl 8192)
__global__ __launch_bounds__(256) void deg_gemm_k(
    const int* __restrict__ curb, const unsigned* __restrict__ pair,
    int* __restrict__ cnt_v,
    const float* __restrict__ X, const float* __restrict__ W,
    const float* __restrict__ bvec, unsigned short* __restrict__ Xpb) {
  __shared__ __align__(16) char smem[DG_SMEM];
  const int t = threadIdx.x;

  if (blockIdx.x < NBKT_V) {
    // ---- deg path ----
    int* rcnt = (int*)smem;
    const int b = blockIdx.x;
    const int base = (NBKT_E + b) * CAP;
    int n = curb[NBKT_E + b];                 // zero-based count
    if (n > CAP) n = CAP;
    if (t < BKT) rcnt[t] = 0;
    __syncthreads();
    for (int j = t; j < n; j += 256) {
      atomicAdd(&rcnt[pair[base + j] & 127u], 1);
    }
    __syncthreads();
    const int v = b * BKT + t;
    if (t < BKT && v < NUM_NODES) cnt_v[v] = rcnt[t];
  } else {
    // ---- gemm path (round-0 proven form) ----
    float* Wl = (float*)smem;                 // [64][65]
    float* Xl = (float*)(smem + 16640);       // [32][64]
    const int g = blockIdx.x - NBKT_V;

    for (int j = t; j < D * D; j += 256) Wl[(j >> 6) * 65 + (j & 63)] = W[j];
    const int row0 = g * GEMM_ROWS;
    const float4* X4 = (const float4*)(X + (size_t)row0 * D);
    float4* Xl4 = (float4*)Xl;
    for (int j = t; j < GEMM_ROWS * (D / 4); j += 256) Xl4[j] = X4[j];
    __syncthreads();

    const int c = t & 63;
    const int rq = t >> 6;
    float acc[8];
#pragma unroll
    for (int i = 0; i < 8; ++i) acc[i] = 0.f;
#pragma unroll
    for (int k = 0; k < D; ++k) {
      const float w = Wl[c * 65 + k];
#pragma unroll
      for (int i = 0; i < 8; ++i)
        acc[i] = fmaf(Xl[(rq + i * 4) * D + k], w, acc[i]);
    }
    const float bias = bvec[c];
#pragma unroll
    for (int i = 0; i < 8; ++i) {
      const int r = row0 + rq + i * 4;
      const float v = acc[i] + bias;
      unsigned u = __float_as_uint(v);
      u = (u + 0x7fffu + ((u >> 16) & 1u)) >> 16;
      Xpb[(size_t)r * D + c] = (unsigned short)u;
    }
  }
}

// ---------------------------------------------------------------------------
// Kernel 3: FUSED edge pass. One block = one edge bucket (128 edges).
// ---------------------------------------------------------------------------
__global__ __launch_bounds__(512) void edge_fused_k(
    const int* __restrict__ curb, const unsigned* __restrict__ pair,
    const int* __restrict__ cnt_v, const uint4* __restrict__ Xpb,
    uint4* __restrict__ Yb) {
  __shared__ unsigned seg[CAP];
  __shared__ int sorted_[CAP];
  __shared__ int rcnt[BKT];
  __shared__ int sc[BKT];
  __shared__ int lcur[BKT];
  const int b = blockIdx.x, t = threadIdx.x;
  const int base = b * CAP;
  int n = curb[b];
  if (n > CAP) n = CAP;
  const int e0 = b * BKT;
  const int nrows = (NUM_EDGES - e0 < BKT) ? (NUM_EDGES - e0) : BKT;

  if (t < BKT) rcnt[t] = 0;
  __syncthreads();

  for (int j = t; j < n; j += 512) {
    const unsigned w = pair[base + j];
    seg[j] = w;
    atomicAdd(&rcnt[w & 127u], 1);
  }
  __syncthreads();

  // single-wave shfl scan of 128 row counts (2 rows per lane)
  if (t < 64) {
    const int a = rcnt[2 * t], bb = rcnt[2 * t + 1];
    int s = a + bb;
#pragma unroll
    for (int d = 1; d < 64; d <<= 1) {
      const int y = __shfl_up(s, d, 64);
      if (t >= d) s += y;
    }
    sc[2 * t + 1] = s;
    sc[2 * t] = s - bb;
    lcur[2 * t + 1] = s - bb;
    lcur[2 * t] = s - bb - a;
  }
  __syncthreads();

  // row-sort member ids into LDS
  for (int j = t; j < n; j += 512) {
    const unsigned w = seg[j];
    const int pos = atomicAdd(&lcur[w & 127u], 1);
    sorted_[pos] = (int)(w >> 7);
  }
  __syncthreads();

  // gather: 8 lanes per row, 64 rows per pass, 2 passes
  const int q = t & 7;
#pragma unroll
  for (int rr = 0; rr < 2; ++rr) {
    const int row = (t >> 3) + rr * 64;
    const int ne = rcnt[row];
    const int mb = sc[row] - ne;
    const int me = sc[row];
    float acc[8];
#pragma unroll
    for (int i = 0; i < 8; ++i) acc[i] = 0.f;
    float dsum = 0.f;
    int m = mb;
    for (; m + 3 < me; m += 4) {
      const int v0 = sorted_[m], v1 = sorted_[m + 1];
      const int v2 = sorted_[m + 2], v3 = sorted_[m + 3];
      const uint4 w0 = Xpb[v0 * 8 + q];
      const uint4 w1 = Xpb[v1 * 8 + q];
      const uint4 w2 = Xpb[v2 * 8 + q];
      const uint4 w3 = Xpb[v3 * 8 + q];
      const float d0 = (float)cnt_v[v0];
      const float d1 = (float)cnt_v[v1];
      const float d2 = (float)cnt_v[v2];
      const float d3 = (float)cnt_v[v3];
      dsum += (d0 + d1) + (d2 + d3);
      acc_row(w0, acc);
      acc_row(w1, acc);
      acc_row(w2, acc);
      acc_row(w3, acc);
    }
    for (; m < me; ++m) {
      const int v = sorted_[m];
      const uint4 w = Xpb[v * 8 + q];
      dsum += (float)cnt_v[v];
      acc_row(w, acc);
    }
    const float ce = (float)ne;
    const float De = dsum / (ce + 1.f);
    const float inv = (De > 0.f) ? rsqrtf(fmaxf(De, 1e-30f)) : 1.f;
    const float s = inv / fmaxf(ce, 1.f);
    if (row < nrows) {
      uint4 o;
      o.x = pack_bf16x2(acc[0] * s, acc[1] * s);
      o.y = pack_bf16x2(acc[2] * s, acc[3] * s);
      o.z = pack_bf16x2(acc[4] * s, acc[5] * s);
      o.w = pack_bf16x2(acc[6] * s, acc[7] * s);
      Yb[(e0 + row) * 8 + q] = o;
    }
  }
}

// ---------------------------------------------------------------------------
// Kernel 4: FUSED node pass. One block = one node bucket (128 nodes).
// ---------------------------------------------------------------------------
__global__ __launch_bounds__(512) void node_fused_k(
    const int* __restrict__ curb, const unsigned* __restrict__ pair,
    const uint4* __restrict__ Yb, float* __restrict__ Out) {
  __shared__ unsigned seg[CAP];
  __shared__ int sorted_[CAP];
  __shared__ int rcnt[BKT];
  __shared__ int sc[BKT];
  __shared__ int lcur[BKT];
  const int b = blockIdx.x, t = threadIdx.x;
  const int base = (NBKT_E + b) * CAP;
  int n = curb[NBKT_E + b];
  if (n > CAP) n = CAP;
  const int v0r = b * BKT;
  const int nrows = (NUM_NODES - v0r < BKT) ? (NUM_NODES - v0r) : BKT;

  if (t < BKT) rcnt[t] = 0;
  __syncthreads();

  for (int j = t; j < n; j += 512) {
    const unsigned w = pair[base + j];
    seg[j] = w;
    atomicAdd(&rcnt[w & 127u], 1);
  }
  __syncthreads();

  if (t < 64) {
    const int a = rcnt[2 * t], bb = rcnt[2 * t + 1];
    int s = a + bb;
#pragma unroll
    for (int d = 1; d < 64; d <<= 1) {
      const int y = __shfl_up(s, d, 64);
      if (t >= d) s += y;
    }
    sc[2 * t + 1] = s;
    sc[2 * t] = s - bb;
    lcur[2 * t + 1] = s - bb;
    lcur[2 * t] = s - bb - a;
  }
  __syncthreads();

  for (int j = t; j < n; j += 512) {
    const unsigned w = seg[j];
    const int pos = atomicAdd(&lcur[w & 127u], 1);
    sorted_[pos] = (int)(w >> 7);
  }
  __syncthreads();

  const int q = t & 7;
#pragma unroll
  for (int rr = 0; rr < 2; ++rr) {
    const int row = (t >> 3) + rr * 64;
    const int dv = rcnt[row];
    const int mb = sc[row] - dv;
    const int me = sc[row];
    float acc[8];
#pragma unroll
    for (int i = 0; i < 8; ++i) acc[i] = 0.f;
    int m = mb;
    for (; m + 3 < me; m += 4) {
      const int e0 = sorted_[m], e1 = sorted_[m + 1];
      const int e2 = sorted_[m + 2], e3 = sorted_[m + 3];
      const uint4 w0 = Yb[e0 * 8 + q];
      const uint4 w1 = Yb[e1 * 8 + q];
      const uint4 w2 = Yb[e2 * 8 + q];
      const uint4 w3 = Yb[e3 * 8 + q];
      acc_row(w0, acc);
      acc_row(w1, acc);
      acc_row(w2, acc);
      acc_row(w3, acc);
    }
    for (; m < me; ++m) {
      acc_row(Yb[sorted_[m] * 8 + q], acc);
    }
    const float d = (float)dv;
    const float s = (d > 0.f) ? rsqrtf(d) : 0.f;
    if (row < nrows) {
      float4* O4 = (float4*)(Out + (size_t)(v0r + row) * D + q * 8);
      O4[0] = make_float4(acc[0] * s, acc[1] * s, acc[2] * s, acc[3] * s);
      O4[1] = make_float4(acc[4] * s, acc[5] * s, acc[6] * s, acc[7] * s);
    }
  }
}

extern "C" void kernel_launch(void* const* d_in, const int* in_sizes, int n_in,
                              void* d_out, int out_size, void* d_ws, size_t ws_size,
                              hipStream_t stream) {
  const float* X = (const float*)d_in[0];
  const int*   V = (const int*)d_in[1];
  const int*   E = (const int*)d_in[2];
  const float* W = (const float*)d_in[4];
  const float* b = (const float*)d_in[5];
  float* Out = (float*)d_out;

  // workspace layout (~44 MB)
  unsigned short* Xpb = (unsigned short*)d_ws;                 // 12.8 MB bf16
  unsigned short* Ybu = Xpb + (size_t)NUM_NODES * D;           // 12.8 MB bf16
  int*      curb   = (int*)(Ybu + (size_t)NUM_EDGES * D);      // 1564 (zero-based)
  int*      cnt_v  = curb + NBKT_TOT;                          // 400 KB
  unsigned* pair   = (unsigned*)(cnt_v + NUM_NODES);           // 17.6 MB

  hipMemsetAsync(curb, 0, NBKT_TOT * sizeof(int), stream);
  bin_tile_k<<<2 * NT_SIDE, 1024, 0, stream>>>(V, E, curb, pair);
  deg_gemm_k<<<NBKT_V + NGEMM, 256, 0, stream>>>(
      curb, pair, cnt_v, X, W, b, Xpb);
  edge_fused_k<<<NBKT_E, 512, 0, stream>>>(
      curb, pair, cnt_v, (const uint4*)Xpb, (uint4*)Ybu);
  node_fused_k<<<NBKT_V, 512, 0, stream>>>(
      curb, pair, (const uint4*)Ybu, Out);
}